// Round 1
// baseline (196.810 us; speedup 1.0000x reference)
//
#include <hip/hip_runtime.h>

// FeatureRestrain: mask[b,c] = (mean(in[b,c,:,:]) >= kth_largest_b) ? 0.8 : 1.2
// in: [64, 2048, 14, 14] f32; out: [64, 2048] f32; k = 1638.

constexpr int B = 64;
constexpr int C = 2048;
constexpr int HW4 = 49;            // 196 floats = 49 float4 per channel
constexpr int K = 1638;            // int(2048 * 0.8)
constexpr int TARGET = C - K;      // 410: 0-based ascending index of k-th largest
constexpr float ALPHA = 0.8f;
constexpr float BETA = 1.2f;

// Monotone map f32 -> u32 (ascending order preserved)
__device__ __forceinline__ unsigned f2key(float f) {
    unsigned b = __float_as_uint(f);
    return (b & 0x80000000u) ? ~b : (b | 0x80000000u);
}

// Kernel 1: global average pool. One wave per channel per iteration.
// Each channel = 49 contiguous float4 (784 B, 16B aligned). Lanes 0..48 load,
// shfl_xor tree-reduce, lane 0 stores the mean as an order-preserving key.
__global__ __launch_bounds__(256) void gap_kernel(
        const float* __restrict__ in, unsigned* __restrict__ keys_out) {
    const int nch = B * C;
    const int gtid = blockIdx.x * blockDim.x + threadIdx.x;
    const int wave = gtid >> 6;
    const int lane = threadIdx.x & 63;
    const int nwaves = (gridDim.x * blockDim.x) >> 6;
    const float4* __restrict__ in4 = reinterpret_cast<const float4*>(in);

    for (int ch = wave; ch < nch; ch += nwaves) {
        float s = 0.0f;
        if (lane < HW4) {
            float4 v = in4[(size_t)ch * HW4 + lane];
            s = (v.x + v.y) + (v.z + v.w);
        }
        #pragma unroll
        for (int off = 32; off >= 1; off >>= 1)
            s += __shfl_xor(s, off, 64);
        if (lane == 0) {
            keys_out[ch] = f2key(s * (1.0f / 196.0f));
        }
    }
}

// Kernel 2: per-row exact radix select (4 passes x 8 bits) + mask write.
// One block per batch row; 2048 keys staged in LDS.
__global__ __launch_bounds__(256) void select_mask_kernel(
        const unsigned* __restrict__ keys_in, float* __restrict__ out) {
    __shared__ unsigned keys[C];
    __shared__ int hist[256];
    __shared__ unsigned s_prefix;
    __shared__ int s_target;

    const int b = blockIdx.x;
    const int tid = threadIdx.x;
    const int nt = blockDim.x;
    const unsigned* __restrict__ row = keys_in + (size_t)b * C;

    for (int i = tid; i < C; i += nt) keys[i] = row[i];
    if (tid == 0) { s_prefix = 0u; s_target = TARGET; }
    __syncthreads();

    #pragma unroll
    for (int pass = 0; pass < 4; ++pass) {
        const int shift = 24 - 8 * pass;
        const unsigned hi_mask = (pass == 0) ? 0u : (0xFFFFFFFFu << (shift + 8));
        for (int i = tid; i < 256; i += nt) hist[i] = 0;
        __syncthreads();
        const unsigned prefix = s_prefix;
        const int target = s_target;
        for (int i = tid; i < C; i += nt) {
            unsigned u = keys[i];
            if ((u & hi_mask) == prefix)
                atomicAdd(&hist[(u >> shift) & 255u], 1);
        }
        __syncthreads();
        if (tid == 0) {
            int cum = 0;
            for (int bin = 0; bin < 256; ++bin) {
                int h = hist[bin];
                if (cum + h > target) {
                    s_prefix = prefix | ((unsigned)bin << shift);
                    s_target = target - cum;
                    break;
                }
                cum += h;
            }
        }
        __syncthreads();
    }

    const unsigned thresh = s_prefix;   // exact key of the k-th largest mean
    float* __restrict__ orow = out + (size_t)b * C;
    for (int i = tid; i < C; i += nt)
        orow[i] = (keys[i] >= thresh) ? ALPHA : BETA;
}

extern "C" void kernel_launch(void* const* d_in, const int* in_sizes, int n_in,
                              void* d_out, int out_size, void* d_ws, size_t ws_size,
                              hipStream_t stream) {
    const float* in = (const float*)d_in[0];
    float* out = (float*)d_out;
    unsigned* keys = (unsigned*)d_ws;   // 64*2048*4 = 512 KB scratch

    gap_kernel<<<2048, 256, 0, stream>>>(in, keys);
    select_mask_kernel<<<B, 256, 0, stream>>>(keys, out);
}

// Round 4
// 151.155 us; speedup vs baseline: 1.3020x; 1.3020x over previous
//
#include <hip/hip_runtime.h>

// FeatureRestrain: mask[b,c] = (mean(in[b,c,:,:]) >= kth_largest_b) ? 0.8 : 1.2
// in: [64, 2048, 14, 14] f32; out: [64, 2048] f32; k = 1638.

constexpr int B = 64;
constexpr int C = 2048;
constexpr int HW4 = 49;            // 196 floats = 49 float4 per channel
constexpr int K = 1638;            // int(2048 * 0.8)
constexpr int TARGET = C - K;      // 410: 0-based ascending index of k-th largest
constexpr float ALPHA = 0.8f;
constexpr float BETA = 1.2f;

constexpr int GAP_BLOCKS = 2048;
constexpr int GAP_THREADS = 256;
constexpr int NWAVES = GAP_BLOCKS * GAP_THREADS / 64;   // 8192
constexpr int CH_PER_WAVE = (B * C) / NWAVES;           // 16

// Monotone map f32 -> u32 (ascending order preserved)
__device__ __forceinline__ unsigned f2key(float f) {
    unsigned b = __float_as_uint(f);
    return (b & 0x80000000u) ? ~b : (b | 0x80000000u);
}

// Kernel 1: global average pool. One wave per channel per iteration.
// 49 contiguous float4 per channel; lanes 0..48 load, shfl_xor tree reduce.
// Trip count hard-coded (16) + unroll 4 so 4 loads/reduction chains overlap.
__global__ __launch_bounds__(256) void gap_kernel(
        const float* __restrict__ in, unsigned* __restrict__ keys_out) {
    const int wave = (blockIdx.x * blockDim.x + threadIdx.x) >> 6;
    const int lane = threadIdx.x & 63;
    const float4* __restrict__ in4 = reinterpret_cast<const float4*>(in);

    #pragma unroll 4
    for (int i = 0; i < CH_PER_WAVE; ++i) {
        const int ch = wave + i * NWAVES;
        float s = 0.0f;
        if (lane < HW4) {
            float4 v = in4[(size_t)ch * HW4 + lane];
            s = (v.x + v.y) + (v.z + v.w);
        }
        #pragma unroll
        for (int off = 32; off >= 1; off >>= 1)
            s += __shfl_xor(s, off, 64);
        if (lane == 0) keys_out[ch] = f2key(s * (1.0f / 196.0f));
    }
}

// Kernel 2: per-row exact radix select (4 passes x 8 bits) + mask write.
// One block per batch row. Fixes vs round 1:
//  - parallel 256-bin prefix scan (shfl_up within wave + cross-wave combine)
//    instead of a tid==0 serial scan with loop-carried LDS reads;
//  - per-wave histogram copies to cut same-address LDS atomic serialization
//    (means cluster into ~12 hot top-byte bins).
__global__ __launch_bounds__(256) void select_mask_kernel(
        const unsigned* __restrict__ keys_in, float* __restrict__ out) {
    __shared__ unsigned keys[C];
    __shared__ int hist[4][256];
    __shared__ int wsum[4];
    __shared__ unsigned s_prefix;
    __shared__ int s_target;

    const int b = blockIdx.x;
    const int tid = threadIdx.x;
    const int lane = tid & 63;
    const int wid = tid >> 6;
    const unsigned* __restrict__ row = keys_in + (size_t)b * C;

    #pragma unroll
    for (int i = 0; i < C / 256; ++i)
        keys[tid + i * 256] = row[tid + i * 256];
    if (tid == 0) { s_prefix = 0u; s_target = TARGET; }
    __syncthreads();

    #pragma unroll
    for (int pass = 0; pass < 4; ++pass) {
        const int shift = 24 - 8 * pass;
        const unsigned hi_mask = (pass == 0) ? 0u : (0xFFFFFFFFu << (shift + 8));

        #pragma unroll
        for (int w = 0; w < 4; ++w) hist[w][tid] = 0;
        const unsigned prefix = s_prefix;   // visible: barrier at end of prev pass
        const int target = s_target;
        __syncthreads();

        #pragma unroll
        for (int i = 0; i < C / 256; ++i) {
            unsigned u = keys[tid + i * 256];
            if ((u & hi_mask) == prefix)
                atomicAdd(&hist[wid][(u >> shift) & 255u], 1);
        }
        __syncthreads();

        const int h = hist[0][tid] + hist[1][tid] + hist[2][tid] + hist[3][tid];
        // inclusive scan over 256 bins: shfl_up within each wave, then combine
        int inc = h;
        #pragma unroll
        for (int off = 1; off < 64; off <<= 1) {
            int n = __shfl_up(inc, off, 64);
            if (lane >= off) inc += n;
        }
        if (lane == 63) wsum[wid] = inc;
        __syncthreads();
        int woff = 0;
        #pragma unroll
        for (int w = 0; w < 4; ++w)
            if (w < wid) woff += wsum[w];
        inc += woff;
        const int exc = inc - h;
        if (exc <= target && target < inc) {   // exactly one thread matches
            s_prefix = prefix | ((unsigned)tid << shift);
            s_target = target - exc;
        }
        __syncthreads();
    }

    const unsigned thresh = s_prefix;   // exact key of the k-th largest mean
    float* __restrict__ orow = out + (size_t)b * C;
    #pragma unroll
    for (int i = 0; i < C / 256; ++i) {
        const int idx = tid + i * 256;
        orow[idx] = (keys[idx] >= thresh) ? ALPHA : BETA;
    }
}

extern "C" void kernel_launch(void* const* d_in, const int* in_sizes, int n_in,
                              void* d_out, int out_size, void* d_ws, size_t ws_size,
                              hipStream_t stream) {
    const float* in = (const float*)d_in[0];
    float* out = (float*)d_out;
    unsigned* keys = (unsigned*)d_ws;   // 64*2048*4 = 512 KB scratch

    gap_kernel<<<GAP_BLOCKS, GAP_THREADS, 0, stream>>>(in, keys);
    select_mask_kernel<<<B, 256, 0, stream>>>(keys, out);
}

// Round 5
// 150.386 us; speedup vs baseline: 1.3087x; 1.0051x over previous
//
#include <hip/hip_runtime.h>

// FeatureRestrain: mask[b,c] = (mean(in[b,c,:,:]) >= kth_largest_b) ? 0.8 : 1.2
// in: [64, 2048, 14, 14] f32; out: [64, 2048] f32; k = 1638.

constexpr int B = 64;
constexpr int C = 2048;
constexpr int HW4 = 49;            // 196 floats = 49 float4 per channel
constexpr int K = 1638;            // int(2048 * 0.8)
constexpr int TARGET = C - K;      // 410: 0-based ascending index of k-th largest
constexpr float ALPHA = 0.8f;
constexpr float BETA = 1.2f;

constexpr int GAP_BLOCKS = 2048;
constexpr int GAP_THREADS = 256;
constexpr int NWAVES = GAP_BLOCKS * GAP_THREADS / 64;   // 8192
constexpr int CH_PER_WAVE = (B * C) / NWAVES;           // 16

// Monotone map f32 -> u32 (ascending order preserved)
__device__ __forceinline__ unsigned f2key(float f) {
    unsigned b = __float_as_uint(f);
    return (b & 0x80000000u) ? ~b : (b | 0x80000000u);
}

// Kernel 1: global average pool. One wave per channel per iteration.
// 49 contiguous float4 per channel; lanes 0..48 load, shfl_xor tree reduce.
// unroll 8: 8 independent 784 B loads in flight per wave to cover ~900-cyc
// HBM-miss latency (4-deep may have been the limiter; BW-bound -> no harm).
__global__ __launch_bounds__(256) void gap_kernel(
        const float* __restrict__ in, unsigned* __restrict__ keys_out) {
    const int wave = (blockIdx.x * blockDim.x + threadIdx.x) >> 6;
    const int lane = threadIdx.x & 63;
    const float4* __restrict__ in4 = reinterpret_cast<const float4*>(in);

    #pragma unroll 8
    for (int i = 0; i < CH_PER_WAVE; ++i) {
        const int ch = wave + i * NWAVES;
        float s = 0.0f;
        if (lane < HW4) {
            float4 v = in4[(size_t)ch * HW4 + lane];
            s = (v.x + v.y) + (v.z + v.w);
        }
        #pragma unroll
        for (int off = 32; off >= 1; off >>= 1)
            s += __shfl_xor(s, off, 64);
        if (lane == 0) keys_out[ch] = f2key(s * (1.0f / 196.0f));
    }
}

// Kernel 2: per-row exact radix select (4 passes x 8 bits) + mask write.
// One block per batch row. Wave-parallel 256-bin prefix scan + per-wave
// histograms (round-4 win). This round: uint4 key load, float4 mask store.
__global__ __launch_bounds__(256) void select_mask_kernel(
        const unsigned* __restrict__ keys_in, float* __restrict__ out) {
    __shared__ unsigned keys[C];
    __shared__ int hist[4][256];
    __shared__ int wsum[4];
    __shared__ unsigned s_prefix;
    __shared__ int s_target;

    const int b = blockIdx.x;
    const int tid = threadIdx.x;
    const int lane = tid & 63;
    const int wid = tid >> 6;
    const uint4* __restrict__ row4 =
        reinterpret_cast<const uint4*>(keys_in + (size_t)b * C);

    // 2048 keys = 512 uint4; 256 threads x 2
    uint4* keys4 = reinterpret_cast<uint4*>(keys);
    #pragma unroll
    for (int i = 0; i < C / 4 / 256; ++i)
        keys4[tid + i * 256] = row4[tid + i * 256];
    if (tid == 0) { s_prefix = 0u; s_target = TARGET; }
    __syncthreads();

    #pragma unroll
    for (int pass = 0; pass < 4; ++pass) {
        const int shift = 24 - 8 * pass;
        const unsigned hi_mask = (pass == 0) ? 0u : (0xFFFFFFFFu << (shift + 8));

        #pragma unroll
        for (int w = 0; w < 4; ++w) hist[w][tid] = 0;
        const unsigned prefix = s_prefix;   // visible: barrier at end of prev pass
        const int target = s_target;
        __syncthreads();

        #pragma unroll
        for (int i = 0; i < C / 256; ++i) {
            unsigned u = keys[tid + i * 256];
            if ((u & hi_mask) == prefix)
                atomicAdd(&hist[wid][(u >> shift) & 255u], 1);
        }
        __syncthreads();

        const int h = hist[0][tid] + hist[1][tid] + hist[2][tid] + hist[3][tid];
        // inclusive scan over 256 bins: shfl_up within each wave, then combine
        int inc = h;
        #pragma unroll
        for (int off = 1; off < 64; off <<= 1) {
            int n = __shfl_up(inc, off, 64);
            if (lane >= off) inc += n;
        }
        if (lane == 63) wsum[wid] = inc;
        __syncthreads();
        int woff = 0;
        #pragma unroll
        for (int w = 0; w < 4; ++w)
            if (w < wid) woff += wsum[w];
        inc += woff;
        const int exc = inc - h;
        if (exc <= target && target < inc) {   // exactly one thread matches
            s_prefix = prefix | ((unsigned)tid << shift);
            s_target = target - exc;
        }
        __syncthreads();
    }

    const unsigned thresh = s_prefix;   // exact key of the k-th largest mean
    float4* __restrict__ orow4 =
        reinterpret_cast<float4*>(out + (size_t)b * C);
    #pragma unroll
    for (int i = 0; i < C / 4 / 256; ++i) {
        const int idx = tid + i * 256;
        uint4 kq = keys4[idx];
        float4 m;
        m.x = (kq.x >= thresh) ? ALPHA : BETA;
        m.y = (kq.y >= thresh) ? ALPHA : BETA;
        m.z = (kq.z >= thresh) ? ALPHA : BETA;
        m.w = (kq.w >= thresh) ? ALPHA : BETA;
        orow4[idx] = m;
    }
}

extern "C" void kernel_launch(void* const* d_in, const int* in_sizes, int n_in,
                              void* d_out, int out_size, void* d_ws, size_t ws_size,
                              hipStream_t stream) {
    const float* in = (const float*)d_in[0];
    float* out = (float*)d_out;
    unsigned* keys = (unsigned*)d_ws;   // 64*2048*4 = 512 KB scratch

    gap_kernel<<<GAP_BLOCKS, GAP_THREADS, 0, stream>>>(in, keys);
    select_mask_kernel<<<B, 256, 0, stream>>>(keys, out);
}